// Round 12
// baseline (231.649 us; speedup 1.0000x reference)
//
#include <hip/hip_runtime.h>
#include <math.h>

#define N_NODES 1500
#define N_EDGES 12000
#define IN_FEAT 512
#define HIDDEN 64
#define OUT_FEAT 32
#define HEADS 8

typedef short bf16x8 __attribute__((ext_vector_type(8)));
typedef float f32x4 __attribute__((ext_vector_type(4)));

__device__ __forceinline__ unsigned short f2bf(float f) {
    unsigned u = __float_as_uint(f);
    u += 0x7fff + ((u >> 16) & 1);   // RNE
    return (unsigned short)(u >> 16);
}
__device__ __forceinline__ float bf2f(unsigned short b) {
    return __uint_as_float(((unsigned)b) << 16);
}
__device__ __forceinline__ unsigned packbf(float a) {
    unsigned short hi = f2bf(a);
    unsigned short lo = f2bf(a - bf2f(hi));
    return (unsigned)hi | ((unsigned)lo << 16);
}
__device__ __forceinline__ float rdlanef(float v, int c) {
    return __uint_as_float(__builtin_amdgcn_readlane(__float_as_uint(v), c));
}

// ---------------- prep: att-eff vectors + W2 reshuffle + W3 hi/lo frags ----
// W4t2[(kg*512 + c)*4 + j] = W2[(kg*4+j)*512 + c]
// wfhi/wflo: [(h*2+nt)*2+ks][lane][4 words]; word j2 = bf16(k=base+2j2) | bf16(k=base+2j2+1)<<16

__global__ void prep_kernel(const float* __restrict__ W2, const float* __restrict__ al2,
                            const float* __restrict__ ar2,
                            const float* __restrict__ W3, const float* __restrict__ al3,
                            const float* __restrict__ ar3,
                            float* __restrict__ aleff2, float* __restrict__ areff2,
                            float* __restrict__ aleff3, float* __restrict__ areff3,
                            float* __restrict__ W4t2,
                            unsigned* __restrict__ wfhi, unsigned* __restrict__ wflo) {
    int i = blockIdx.x * blockDim.x + threadIdx.x;
    if (i < 1024) {  // aleff2 / areff2
        int lr = i >> 9; i &= 511;
        int h = i >> 6, k = i & 63;
        const float* a = lr ? ar2 : al2;
        float s = 0.f;
        for (int f = 0; f < 64; ++f)
            s = fmaf(W2[(size_t)k * 512 + h * 64 + f], a[h * 64 + f], s);
        (lr ? areff2 : aleff2)[h * 64 + k] = s;
        return;
    }
    i -= 1024;
    if (i < 1024) {  // aleff3 / areff3
        int lr = i >> 9; i &= 511;
        int h = i >> 6, k = i & 63;
        const float* a = lr ? ar3 : al3;
        float s = 0.f;
        for (int f = 0; f < 32; ++f)
            s = fmaf(W3[(size_t)k * 256 + h * 32 + f], a[h * 32 + f], s);
        (lr ? areff3 : aleff3)[h * 64 + k] = s;
        return;
    }
    i -= 1024;
    if (i < 16 * 512 * 4) {  // W4t2
        int kg = i >> 11, rem = i & 2047;
        int c = rem >> 2, j = rem & 3;
        W4t2[i] = W2[(size_t)(kg * 4 + j) * 512 + c];
        return;
    }
    i -= 16 * 512 * 4;
    if (i < 16384) {  // wfhi / wflo
        int plane = i >> 13;
        int rem = i & 8191;
        int j2 = rem & 3, l = (rem >> 2) & 63;
        int ks = (rem >> 8) & 1, nt = (rem >> 9) & 1, h = (rem >> 10) & 7;
        int col = h * 32 + nt * 16 + (l & 15);
        int kb = ks * 32 + (l >> 4) * 8 + 2 * j2;
        unsigned parts[2];
        #pragma unroll
        for (int q = 0; q < 2; ++q) {
            float w = W3[(size_t)(kb + q) * 256 + col];
            unsigned short hi = f2bf(w);
            parts[q] = plane ? (unsigned)f2bf(w - bf2f(hi)) : (unsigned)hi;
        }
        unsigned word = parts[0] | (parts[1] << 16);
        (plane ? wflo : wfhi)[rem] = word;
    }
}

// ---------------- single-block CSR build: hist + scan + scatter + stable-order sort ------
// One 1024-thread block; all intermediates in LDS. Deterministic (rank by edge id).
__global__ __launch_bounds__(1024) void csr_build_kernel(
    const int* __restrict__ dst, const int* __restrict__ src,
    int* __restrict__ row_ptr, int* __restrict__ csr_src) {
    __shared__ int cnt[N_NODES + 1];
    __shared__ int rp[N_NODES + 1];
    __shared__ int eid[N_EDGES];
    __shared__ int part[1024];
    int t = threadIdx.x;
    for (int i = t; i <= N_NODES; i += 1024) cnt[i] = 0;
    __syncthreads();
    for (int e = t; e < N_EDGES; e += 1024) atomicAdd(&cnt[dst[e]], 1);
    __syncthreads();
    // exclusive scan over 1501 entries (2 per thread)
    int base = t * 2;
    int v0 = (base < N_NODES) ? cnt[base] : 0;
    int v1 = (base + 1 < N_NODES) ? cnt[base + 1] : 0;
    part[t] = v0 + v1;
    __syncthreads();
    if (t == 0) {
        int a = 0;
        for (int i = 0; i < 1024; ++i) { int v = part[i]; part[i] = a; a += v; }
        rp[N_NODES] = a;
    }
    __syncthreads();
    if (base < N_NODES) rp[base] = part[t];
    if (base + 1 < N_NODES) rp[base + 1] = part[t] + v0;
    __syncthreads();
    for (int i = t; i <= N_NODES; i += 1024) row_ptr[i] = rp[i];
    for (int i = t; i <= N_NODES; i += 1024) cnt[i] = 0;   // reuse as cursor
    __syncthreads();
    for (int e = t; e < N_EDGES; e += 1024) {
        int d = dst[e];
        int pos = rp[d] + atomicAdd(&cnt[d], 1);
        eid[pos] = e;
    }
    __syncthreads();
    // per-node rank sort by edge id (stable order), wave per node
    int wv = t >> 6, lane = t & 63;
    for (int nd = wv; nd < N_NODES; nd += 16) {
        int r0 = rp[nd], deg = rp[nd + 1] - r0;
        for (int b0 = 0; b0 < deg; b0 += 64) {
            int i = b0 + lane;
            int my = (i < deg) ? eid[r0 + i] : 0x7fffffff;
            int rank = 0;
            for (int j = 0; j < deg; ++j) {
                int oj = eid[r0 + j];
                rank += (oj < my) ? 1 : 0;
            }
            if (i < deg) csr_src[r0 + rank] = src[my];
        }
    }
}

// ---------------- f32 tiled GEMM (layer 1): 32x32 tiles (752 blocks) ----------

#define GM 32
#define GN 32
#define GK 32

__global__ __launch_bounds__(256) void gemm_f32(const float* __restrict__ A,
                                                const float* __restrict__ B,
                                                float* __restrict__ C,
                                                int M, int N, int K) {
    __shared__ float As[GK][GM + 2];
    __shared__ float Bs[GK][GN + 2];
    int t = threadIdx.x;
    int col0 = blockIdx.x * GN, row0 = blockIdx.y * GM;
    int tx = t & 15, ty = t >> 4;
    int am = t >> 3, ak = (t & 7) * 4;
    int bk = t >> 3, bn = (t & 7) * 4;
    float acc[2][2] = {};
    for (int k0 = 0; k0 < K; k0 += GK) {
        int gr = row0 + am;
        float4 av = (gr < M) ? *(const float4*)&A[(size_t)gr * K + k0 + ak]
                             : make_float4(0.f, 0.f, 0.f, 0.f);
        float4 bv = *(const float4*)&B[(size_t)(k0 + bk) * N + col0 + bn];
        __syncthreads();
        As[ak + 0][am] = av.x; As[ak + 1][am] = av.y;
        As[ak + 2][am] = av.z; As[ak + 3][am] = av.w;
        *(float4*)&Bs[bk][bn] = bv;
        __syncthreads();
        #pragma unroll
        for (int kk = 0; kk < GK; ++kk) {
            float2 a2 = *(const float2*)&As[kk][ty * 2];
            float2 b2 = *(const float2*)&Bs[kk][tx * 2];
            acc[0][0] = fmaf(a2.x, b2.x, acc[0][0]);
            acc[0][1] = fmaf(a2.x, b2.y, acc[0][1]);
            acc[1][0] = fmaf(a2.y, b2.x, acc[1][0]);
            acc[1][1] = fmaf(a2.y, b2.y, acc[1][1]);
        }
    }
    #pragma unroll
    for (int i = 0; i < 2; ++i) {
        int gr = row0 + ty * 2 + i;
        if (gr < M) {
            float2 v = make_float2(acc[i][0], acc[i][1]);
            *(float2*)&C[(size_t)gr * N + col0 + tx * 2] = v;
        }
    }
}

// ---------------- el/er kernels ----------------

__global__ void elr_feat_kernel(const float* __restrict__ feat, const float* __restrict__ al,
                                const float* __restrict__ ar, float* __restrict__ el,
                                float* __restrict__ er, int RH) {
    int idx = blockIdx.x * blockDim.x + threadIdx.x;
    if (idx >= RH) return;
    int h = idx & (HEADS - 1);
    const float* fp = feat + (size_t)idx * HIDDEN;
    float sl = 0.f, sr = 0.f;
    for (int f = 0; f < HIDDEN; ++f) {
        float v = fp[f];
        sl = fmaf(v, al[h * HIDDEN + f], sl);
        sr = fmaf(v, ar[h * HIDDEN + f], sr);
    }
    el[idx] = sl;
    er[idx] = sr;
}

__global__ void elr_row_kernel(const float* __restrict__ X, const float* __restrict__ alv,
                               const float* __restrict__ arv, float* __restrict__ el,
                               float* __restrict__ er, int R) {
    int r = blockIdx.x * blockDim.x + threadIdx.x;
    if (r >= R) return;
    const float4* x4 = (const float4*)(X + (size_t)r * 64);
    float sl[8] = {}, sr[8] = {};
    for (int kg = 0; kg < 16; ++kg) {
        float4 xv = x4[kg];
        #pragma unroll
        for (int h = 0; h < 8; ++h) {
            float4 a = *(const float4*)&alv[h * 64 + kg * 4];
            float4 b = *(const float4*)&arv[h * 64 + kg * 4];
            sl[h] = fmaf(xv.x, a.x, fmaf(xv.y, a.y, fmaf(xv.z, a.z, fmaf(xv.w, a.w, sl[h]))));
            sr[h] = fmaf(xv.x, b.x, fmaf(xv.y, b.y, fmaf(xv.z, b.z, fmaf(xv.w, b.w, sr[h]))));
        }
    }
    float* elp = el + (size_t)r * 8;
    float* erp = er + (size_t)r * 8;
    #pragma unroll
    for (int h = 0; h < 8; ++h) { elp[h] = sl[h]; erp[h] = sr[h]; }
}

__device__ __forceinline__ float gelu_exact(float v) {
    return 0.5f * v * (1.0f + erff(v * 0.70710678118654752440f));
}

// ---------------- layer-1 aggregation: wave per (node, head-pair), src in registers ----------
__global__ __launch_bounds__(256) void agg_l1(
    const float* __restrict__ feat, const float* __restrict__ el, const float* __restrict__ er,
    const float* __restrict__ bias, const int* __restrict__ row_ptr,
    const int* __restrict__ csr_src, float* __restrict__ out) {
    int n = blockIdx.x;
    int t = threadIdx.x, wv = t >> 6, lane = t & 63;
    int h0 = 2 * wv;
    int r0 = row_ptr[n], deg = row_ptr[n + 1] - r0;
    float2 erv = *(const float2*)&er[n * 8 + h0];
    float den0 = 0.f, den1 = 0.f, a0 = 0.f, a1 = 0.f;
    for (int c0 = 0; c0 < deg; c0 += 64) {
        int cnt = min(deg - c0, 64);
        int src_r = (lane < cnt) ? csr_src[r0 + c0 + lane] : 0;
        auto do_edge = [&](int s) {
            float2 elv = *(const float2*)&el[s * 8 + h0];
            float x0 = feat[((size_t)s * 8 + h0) * 64 + lane];
            float x1 = feat[((size_t)s * 8 + h0 + 1) * 64 + lane];
            float e0 = elv.x + erv.x; e0 = e0 > 0.f ? e0 : 0.2f * e0;
            float e1 = elv.y + erv.y; e1 = e1 > 0.f ? e1 : 0.2f * e1;
            float w0 = __expf(e0), w1 = __expf(e1);
            den0 += w0; den1 += w1;
            a0 = fmaf(w0, x0, a0);
            a1 = fmaf(w1, x1, a1);
        };
        int i = 0;
        for (; i + 2 <= cnt; i += 2) {
            int s0 = __builtin_amdgcn_readlane(src_r, i);
            int s1 = __builtin_amdgcn_readlane(src_r, i + 1);
            do_edge(s0);
            do_edge(s1);
        }
        if (i < cnt) do_edge(__builtin_amdgcn_readlane(src_r, i));
    }
    float i0 = deg ? 1.f / den0 : 0.f;
    float i1 = deg ? 1.f / den1 : 0.f;
    float v0 = a0 * i0 + bias[h0 * 64 + lane];
    float v1 = a1 * i1 + bias[(h0 + 1) * 64 + lane];
    out[((size_t)n * 8 + h0) * 64 + lane] = gelu_exact(v0);
    out[((size_t)n * 8 + h0 + 1) * 64 + lane] = gelu_exact(v1);
}

// ---------------- layer 2: agg + transform + FUSED el3/er3 (elr_row-L3 absorbed) ----------
// LDS 35.1 KB -> 4 blocks/CU. Phase R: 16-lane fq-groups hold one h2 row; shfl_xor reduce
// gives el3/er3 = h2row . aleff3/areff3 without a separate 24.6MB-reading kernel.
__global__ __launch_bounds__(256, 4) void agg_fused5(
    const float* __restrict__ X,     // h1 [N*8, 64]
    const float* __restrict__ el, const float* __restrict__ er,  // [N*8, 8]
    const float* __restrict__ W4t,   // [16][512][4]
    const float* __restrict__ bias,  // [512]
    const float* __restrict__ alv3, const float* __restrict__ arv3,  // [8][64]
    const int* __restrict__ row_ptr, const int* __restrict__ csr_src,
    float* __restrict__ out,         // h2 [N*8, 512]
    float* __restrict__ el3, float* __restrict__ er3)  // [N*64, 8]
{
    constexpr int TOT = 512;
    constexpr int PTS = 68;
    constexpr int CHUNK = 64;

    int n = blockIdx.x;
    int r0 = row_ptr[n], deg = row_ptr[n + 1] - r0;
    int t = threadIdx.x, wv = t >> 6, lane = t & 63;

    __shared__ float inv_s[64];
    __shared__ float acc_s[8][8][68];
    __shared__ float wp_lds[64 * PTS];

    float agg0[8], agg1[8];
    #pragma unroll
    for (int h = 0; h < 8; ++h) { agg0[h] = 0.f; agg1[h] = 0.f; }
    float den = 0.f;

    int elbase_n = n * 8 * 8;
    int pA = wv * 2;
    float erv_t = er[elbase_n + lane];

    for (int c0 = 0; c0 < deg; c0 += CHUNK) {
        int cnt = min(deg - c0, CHUNK);
        int src_r = (lane < cnt) ? csr_src[r0 + c0 + lane] : 0;
        __syncthreads();
        for (int j = t; j < cnt * 64; j += 256) {
            int i = j >> 6;
            int s = __builtin_amdgcn_readlane(src_r, i);
            float e = el[(s * 8) * 8 + lane] + erv_t;
            e = e > 0.f ? e : 0.2f * e;
            wp_lds[i * 64 + lane] = __expf(e);
        }
        __syncthreads();
        if (t < 64) {
            for (int i = 0; i < cnt; ++i) den += wp_lds[i * 64 + t];
        }
        auto edge_fma = [&](int i) {
            int s = __builtin_amdgcn_readlane(src_r, i);
            const float* wp = &wp_lds[i * 64 + wv * 16];
            float4 w0 = *(const float4*)wp;
            float4 w1 = *(const float4*)(wp + 4);
            float4 w2 = *(const float4*)(wp + 8);
            float4 w3 = *(const float4*)(wp + 12);
            int xb = (s * 8 + pA) * 64 + lane;
            float xv0 = X[xb];
            float xv1 = X[xb + 64];
            agg0[0] = fmaf(w0.x, xv0, agg0[0]);
            agg0[1] = fmaf(w0.y, xv0, agg0[1]);
            agg0[2] = fmaf(w0.z, xv0, agg0[2]);
            agg0[3] = fmaf(w0.w, xv0, agg0[3]);
            agg0[4] = fmaf(w1.x, xv0, agg0[4]);
            agg0[5] = fmaf(w1.y, xv0, agg0[5]);
            agg0[6] = fmaf(w1.z, xv0, agg0[6]);
            agg0[7] = fmaf(w1.w, xv0, agg0[7]);
            agg1[0] = fmaf(w2.x, xv1, agg1[0]);
            agg1[1] = fmaf(w2.y, xv1, agg1[1]);
            agg1[2] = fmaf(w2.z, xv1, agg1[2]);
            agg1[3] = fmaf(w2.w, xv1, agg1[3]);
            agg1[4] = fmaf(w3.x, xv1, agg1[4]);
            agg1[5] = fmaf(w3.y, xv1, agg1[5]);
            agg1[6] = fmaf(w3.z, xv1, agg1[6]);
            agg1[7] = fmaf(w3.w, xv1, agg1[7]);
        };
        int i = 0;
        for (; i + 2 <= cnt; i += 2) { edge_fma(i); edge_fma(i + 1); }
        if (i < cnt) edge_fma(i);
    }
    if (t < 64) inv_s[t] = deg ? 1.f / den : 0.f;
    __syncthreads();
    {
        int pl0 = wv * 2;
        #pragma unroll
        for (int h = 0; h < 8; ++h) {
            acc_s[pl0][h][lane] = agg0[h] * inv_s[pl0 * 8 + h];
            acc_s[pl0 + 1][h][lane] = agg1[h] * inv_s[pl0 * 8 + 8 + h];
        }
    }
    __syncthreads();

    // Phase T: thread = (h = t>>5, ft = t&31); 2 outputs f0 = ft*2, all 16 kg.
    {
        int h = t >> 5, ft = t & 31;
        int f0 = ft * 2;
        float part[8][2];
        #pragma unroll
        for (int pl = 0; pl < 8; ++pl) { part[pl][0] = 0.f; part[pl][1] = 0.f; }
        #pragma unroll
        for (int kg = 0; kg < 16; ++kg) {
            float4 wr0 = *(const float4*)&W4t[(size_t)(kg * TOT + h * 64 + f0 + 0) * 4];
            float4 wr1 = *(const float4*)&W4t[(size_t)(kg * TOT + h * 64 + f0 + 1) * 4];
            #pragma unroll
            for (int pl = 0; pl < 8; ++pl) {
                float4 a4 = *(const float4*)&acc_s[pl][h][kg * 4];
                part[pl][0] = fmaf(a4.x, wr0.x, fmaf(a4.y, wr0.y,
                              fmaf(a4.z, wr0.z, fmaf(a4.w, wr0.w, part[pl][0]))));
                part[pl][1] = fmaf(a4.x, wr1.x, fmaf(a4.y, wr1.y,
                              fmaf(a4.z, wr1.z, fmaf(a4.w, wr1.w, part[pl][1]))));
            }
        }
        __syncthreads();   // weights buffer dead; reuse as partials
        #pragma unroll
        for (int pl = 0; pl < 8; ++pl)
            *(float2*)&wp_lds[(pl * 8 + h) * PTS + f0] = make_float2(part[pl][0], part[pl][1]);
    }
    __syncthreads();

    // Phase R: bias + gelu + store h2 + fused el3/er3.
    // Thread-constant (h, fq); pl varies per iteration. 16 fq-lanes = one h2 row.
    {
        int rem = t & 127;
        int h = rem >> 4, fq = rem & 15;
        int f0 = fq * 4;
        #pragma unroll
        for (int it = 0; it < 4; ++it) {
            int pl = (t >> 7) + 2 * it;
            float4 acc4 = *(const float4*)&wp_lds[(pl * 8 + h) * PTS + f0];
            float4 b4 = *(const float4*)&bias[h * 64 + f0];
            acc4.x = gelu_exact(acc4.x + b4.x);
            acc4.y = gelu_exact(acc4.y + b4.y);
            acc4.z = gelu_exact(acc4.z + b4.z);
            acc4.w = gelu_exact(acc4.w + b4.w);
            *(float4*)&out[(size_t)(n * 8 + pl) * TOT + h * 64 + f0] = acc4;
            // fused el3/er3 for h2 row p = pl*8 + h
            float sel = 0.f;
            #pragma unroll
            for (int j = 0; j < 8; ++j) {
                float4 a4 = *(const float4*)&alv3[j * 64 + f0];
                float4 r4 = *(const float4*)&arv3[j * 64 + f0];
                float pe = fmaf(acc4.x, a4.x, fmaf(acc4.y, a4.y,
                           fmaf(acc4.z, a4.z, acc4.w * a4.w)));
                float pr = fmaf(acc4.x, r4.x, fmaf(acc4.y, r4.y,
                           fmaf(acc4.z, r4.z, acc4.w * r4.w)));
                #pragma unroll
                for (int m = 1; m < 16; m <<= 1) {
                    pe += __shfl_xor(pe, m);
                    pr += __shfl_xor(pr, m);
                }
                sel = (fq == j) ? pe : sel;
                sel = (fq == 8 + j) ? pr : sel;
            }
            int p = pl * 8 + h;
            size_t rbase = ((size_t)n * 64 + p) * 8;
            float* dstp = (fq < 8) ? &el3[rbase + fq] : &er3[rbase + (fq - 8)];
            *dstp = sel;
        }
    }
}

// ---------------- layer 3: register-src aggregation + split-h MFMA transform ----------------
// Block = (node, 16-p group), 6000 blocks, 6 blocks/CU (r10 best). Nontemporal out stores:
// out is write-once; keep it out of L2 so the X-gather keeps its hit rate.
__global__ __launch_bounds__(256, 6) void agg_mfma6(
    const float* __restrict__ X,        // h2 [N*64, 64]
    const float* __restrict__ el, const float* __restrict__ er,  // [N*64, 8]
    const unsigned* __restrict__ wfhi, const unsigned* __restrict__ wflo,
    const float* __restrict__ bias,     // [256]
    const int* __restrict__ row_ptr, const int* __restrict__ csr_src,
    float* __restrict__ out)            // [N*64, 256]
{
    int b = blockIdx.x;                  // 6000 = 1500 n * 4 pg
    int n = b >> 2, pg = b & 3;
    int p0 = pg * 16;
    int r0 = row_ptr[n], deg = row_ptr[n + 1] - r0;
    int t = threadIdx.x, wv = t >> 6, lane = t & 63;
    int pA = p0 + wv * 4;

    __shared__ unsigned accH[4][16][68];   // [h in round][pl][k] packed bf16 hi|lo

    int c = lane & 31;                     // (q,h) = (c>>3, c&7)
    float erv = er[(n * 64 + pA) * 8 + c];

    float agg[4][8];
    #pragma unroll
    for (int q = 0; q < 4; ++q)
        #pragma unroll
        for (int h = 0; h < 8; ++h) agg[q][h] = 0.f;
    float den_half = 0.f;

    for (int c0 = 0; c0 < deg; c0 += 64) {
        int cnt = min(deg - c0, 64);
        int src_r = (lane < cnt) ? csr_src[r0 + c0 + lane] : 0;
        for (int it = 0; it < cnt; it += 4) {
            int i1 = min(it + 1, cnt - 1), i2 = min(it + 2, cnt - 1), i3 = min(it + 3, cnt - 1);
            int s0 = __builtin_amdgcn_readlane(src_r, it);
            int s1 = __builtin_amdgcn_readlane(src_r, i1);
            int s2 = __builtin_amdgcn_readlane(src_r, i2);
            int s3 = __builtin_amdgcn_readlane(src_r, i3);
            bool v1 = it + 1 < cnt, v2 = it + 2 < cnt, v3 = it + 3 < cnt;
            int sA = (lane < 32) ? s0 : s1;
            int sB = (lane < 32) ? s2 : s3;
            float eA = el[(sA * 64 + pA) * 8 + c] + erv;
            float eB = el[(sB * 64 + pA) * 8 + c] + erv;
            eA = eA > 0.f ? eA : 0.2f * eA;
            eB = eB > 0.f ? eB : 0.2f * eB;
            if (lane >= 32 && !v1) eA = -1e30f;
            if (lane < 32 && !v2) eB = -1e30f;
            if (lane >= 32 && !v3) eB = -1e30f;
            float wA = __expf(eA), wB = __expf(eB);
            den_half += wA + wB;
            int xb0 = (s0 * 64 + pA) * 64 + lane;
            int xb1 = (s1 * 64 + pA) * 64 + lane;
            int xb2 = (s2 * 64 + pA) * 64 + lane;
            int xb3 = (s3 * 64 + pA) * 64 + lane;
            float x0[4], x1[4], x2[4], x3[4];
            #pragma unroll
            for (int q = 0; q < 4; ++q) x0[q] = X[xb0 + q * 64];
            #pragma unroll
            for (int q = 0; q < 4; ++q) x1[q] = X[xb1 + q * 64];
            #pragma unroll
            for (int q = 0; q < 4; ++q) x2[q] = X[xb2 + q * 64];
            #pragma unroll
            for (int q = 0; q < 4; ++q) x3[q] = X[xb3 + q * 64];
            #pragma unroll
            for (int q = 0; q < 4; ++q) {
                #pragma unroll
                for (int h = 0; h < 8; ++h) {
                    agg[q][h] = fmaf(rdlanef(wA, q * 8 + h), x0[q], agg[q][h]);
                    agg[q][h] = fmaf(rdlanef(wA, 32 + q * 8 + h), x1[q], agg[q][h]);
                    agg[q][h] = fmaf(rdlanef(wB, q * 8 + h), x2[q], agg[q][h]);
                    agg[q][h] = fmaf(rdlanef(wB, 32 + q * 8 + h), x3[q], agg[q][h]);
                }
            }
        }
    }
    float den = den_half + __shfl(den_half, lane ^ 32);
    float inv = deg ? 1.f / den : 0.f;

    int m16 = lane & 15, g = lane >> 4;
    #pragma unroll
    for (int r = 0; r < 2; ++r) {
        if (r) __syncthreads();   // prev round's MFMA reads done before overwrite
        #pragma unroll
        for (int q = 0; q < 4; ++q) {
            int pl = wv * 4 + q;
            #pragma unroll
            for (int hh = 0; hh < 4; ++hh) {
                int h = 4 * r + hh;
                float iv = rdlanef(inv, q * 8 + h);
                accH[hh][pl][lane] = packbf(agg[q][h] * iv);
            }
        }
        __syncthreads();
        int h = 4 * r + wv;
        bf16x8 a_hi[2], a_lo[2];
        #pragma unroll
        for (int ks = 0; ks < 2; ++ks) {
            const unsigned* ap = &accH[wv][m16][ks * 32 + g * 8];
            uint4 q0 = *(const uint4*)ap;
            uint4 q1 = *(const uint4*)(ap + 4);
            a_hi[ks][0] = (short)(q0.x & 0xffffu); a_lo[ks][0] = (short)(q0.x >> 16);
            a_hi[ks][1] = (short)(q0.y & 0xffffu); a_lo[ks][1] = (short)(q0.y >> 16);
            a_hi[ks][2] = (short)(q0.z & 0xffffu); a_lo[ks][2] = (short)(q0.z >> 16);
            a_hi[ks][3] = (short)(q0.w & 0xffffu); a_lo[ks][3] = (short)(q0.w >> 16);
            a_hi[ks][4] = (short)(q1.x & 0xffffu); a_lo[ks][4] = (short)(q1.x >> 16);
            a_hi[ks][5] = (short)(q1.y & 0xffffu); a_lo[ks][5] = (short)(q1.y >> 16);
            a_hi[ks][6] = (short)(q1.z & 0xffffu); a_lo[ks][6] = (short)(q1.z >> 16);
            a_hi[ks][7] = (short)(q1.w & 0xffffu); a_lo[ks][7] = (short)(q1.w >> 16);
        }
        #pragma unroll
        for (int nt = 0; nt < 2; ++nt) {
            f32x4 D = {0.f, 0.f, 0.f, 0.f};
            #pragma unroll
            for (int ks = 0; ks < 2; ++ks) {
                size_t fb = (size_t)(((h * 2 + nt) * 2 + ks) * 64 + lane) * 4;
                bf16x8 b_hi = *(const bf16x8*)&wfhi[fb];
                bf16x8 b_lo = *(const bf16x8*)&wflo[fb];
                D = __builtin_amdgcn_mfma_f32_16x16x32_bf16(a_hi[ks], b_hi, D, 0, 0, 0);
                D = __builtin_amdgcn_mfma_f32_16x16x32_bf16(a_hi[ks], b_lo, D, 0, 0, 0);
                D = __builtin_amdgcn_mfma_f32_16x16x32_bf16(a_lo[ks], b_hi, D, 0, 0, 0);
            }
            float bv = bias[h * 32 + nt * 16 + m16];
            size_t ob = ((size_t)(n * 64) + p0 + g * 4) * 256 + h * 32 + nt * 16 + m16;
            __builtin_nontemporal_store(D[0] + bv, &out[ob]);
            __builtin_nontemporal_store(D[1] + bv, &out[ob + 256]);
            __builtin_nontemporal_store(D[2] + bv, &out[ob + 512]);
            __builtin_nontemporal_store(D[3] + bv, &out[ob + 768]);
        }
    }
}

// ---------------- launch ----------------

extern "C" void kernel_launch(void* const* d_in, const int* in_sizes, int n_in,
                              void* d_out, int out_size, void* d_ws, size_t ws_size,
                              hipStream_t stream) {
    const float* node = (const float*)d_in[0];
    const int* src = (const int*)d_in[1];
    const int* dst = (const int*)d_in[2];
    const float* W1 = (const float*)d_in[3];
    const float* al1 = (const float*)d_in[4];
    const float* ar1 = (const float*)d_in[5];
    const float* b1 = (const float*)d_in[6];
    const float* W2 = (const float*)d_in[7];
    const float* al2 = (const float*)d_in[8];
    const float* ar2 = (const float*)d_in[9];
    const float* b2 = (const float*)d_in[10];
    const float* W3 = (const float*)d_in[11];
    const float* al3 = (const float*)d_in[12];
    const float* ar3 = (const float*)d_in[13];
    const float* b3 = (const float*)d_in[14];
    float* out = (float*)d_out;

    char* ws = (char*)d_ws;
    size_t off = 0;
    auto alloc = [&](size_t nb) -> char* {
        char* q = ws + off;
        off += (nb + 255) & ~(size_t)255;
        return q;
    };
    int* row_ptr  = (int*)alloc((N_NODES + 1) * sizeof(int));
    int* csr_src  = (int*)alloc(N_EDGES * sizeof(int));
    float* feat1  = (float*)alloc((size_t)N_NODES * 8 * 64 * 4);
    float* el1    = (float*)alloc((size_t)N_NODES * 8 * 4);
    float* er1    = (float*)alloc((size_t)N_NODES * 8 * 4);
    float* h1     = (float*)alloc((size_t)N_NODES * 8 * 64 * 4);
    float* aleff2 = (float*)alloc(8 * 64 * 4);
    float* areff2 = (float*)alloc(8 * 64 * 4);
    float* el2    = (float*)alloc((size_t)N_NODES * 8 * 8 * 4);
    float* er2    = (float*)alloc((size_t)N_NODES * 8 * 8 * 4);
    float* h2     = (float*)alloc((size_t)N_NODES * 64 * 64 * 4);
    float* aleff3 = (float*)alloc(8 * 64 * 4);
    float* areff3 = (float*)alloc(8 * 64 * 4);
    float* el3    = (float*)alloc((size_t)N_NODES * 64 * 8 * 4);
    float* er3    = (float*)alloc((size_t)N_NODES * 64 * 8 * 4);
    float* W4t2   = (float*)alloc((size_t)16 * 512 * 4 * 4);
    unsigned* wfhi = (unsigned*)alloc((size_t)8192 * 4);
    unsigned* wflo = (unsigned*)alloc((size_t)8192 * 4);

    const int PREP_T = 1024 + 1024 + 16 * 512 * 4 + 16384;
    prep_kernel<<<(PREP_T + 255) / 256, 256, 0, stream>>>(
        W2, al2, ar2, W3, al3, ar3, aleff2, areff2, aleff3, areff3, W4t2, wfhi, wflo);

    csr_build_kernel<<<1, 1024, 0, stream>>>(dst, src, row_ptr, csr_src);

    // ---- layer 1 ----
    dim3 g1((512 + GN - 1) / GN, (N_NODES + GM - 1) / GM);
    gemm_f32<<<g1, 256, 0, stream>>>(node, W1, feat1, N_NODES, 512, IN_FEAT);
    elr_feat_kernel<<<(N_NODES * 8 + 255) / 256, 256, 0, stream>>>(feat1, al1, ar1, el1, er1, N_NODES * 8);
    agg_l1<<<N_NODES, 256, 0, stream>>>(feat1, el1, er1, b1, row_ptr, csr_src, h1);

    // ---- layer 2 (el3/er3 fused into epilogue) ----
    elr_row_kernel<<<(N_NODES * 8 + 255) / 256, 256, 0, stream>>>(h1, aleff2, areff2, el2, er2, N_NODES * 8);
    agg_fused5<<<N_NODES, 256, 0, stream>>>(h1, el2, er2, W4t2, b2, aleff3, areff3,
                                            row_ptr, csr_src, h2, el3, er3);

    // ---- layer 3 ----
    agg_mfma6<<<N_NODES * 4, 256, 0, stream>>>(h2, el3, er3, wfhi, wflo, b3, row_ptr, csr_src, out);
}

// Round 13
// 222.494 us; speedup vs baseline: 1.0411x; 1.0411x over previous
//
#include <hip/hip_runtime.h>
#include <math.h>

#define N_NODES 1500
#define N_EDGES 12000
#define IN_FEAT 512
#define HIDDEN 64
#define OUT_FEAT 32
#define HEADS 8

typedef short bf16x8 __attribute__((ext_vector_type(8)));
typedef float f32x4 __attribute__((ext_vector_type(4)));

__device__ __forceinline__ unsigned short f2bf(float f) {
    unsigned u = __float_as_uint(f);
    u += 0x7fff + ((u >> 16) & 1);   // RNE
    return (unsigned short)(u >> 16);
}
__device__ __forceinline__ float bf2f(unsigned short b) {
    return __uint_as_float(((unsigned)b) << 16);
}
__device__ __forceinline__ unsigned packbf(float a) {
    unsigned short hi = f2bf(a);
    unsigned short lo = f2bf(a - bf2f(hi));
    return (unsigned)hi | ((unsigned)lo << 16);
}
__device__ __forceinline__ float rdlanef(float v, int c) {
    return __uint_as_float(__builtin_amdgcn_readlane(__float_as_uint(v), c));
}

// ---------------- prep: att-eff vectors + W2 reshuffle + W3 hi/lo frags ----
// W4t2[(kg*512 + c)*4 + j] = W2[(kg*4+j)*512 + c]
// wfhi/wflo: [(h*2+nt)*2+ks][lane][4 words]; word j2 = bf16(k=base+2j2) | bf16(k=base+2j2+1)<<16

__global__ void prep_kernel(const float* __restrict__ W2, const float* __restrict__ al2,
                            const float* __restrict__ ar2,
                            const float* __restrict__ W3, const float* __restrict__ al3,
                            const float* __restrict__ ar3,
                            float* __restrict__ aleff2, float* __restrict__ areff2,
                            float* __restrict__ aleff3, float* __restrict__ areff3,
                            float* __restrict__ W4t2,
                            unsigned* __restrict__ wfhi, unsigned* __restrict__ wflo) {
    int i = blockIdx.x * blockDim.x + threadIdx.x;
    if (i < 1024) {  // aleff2 / areff2
        int lr = i >> 9; i &= 511;
        int h = i >> 6, k = i & 63;
        const float* a = lr ? ar2 : al2;
        float s = 0.f;
        for (int f = 0; f < 64; ++f)
            s = fmaf(W2[(size_t)k * 512 + h * 64 + f], a[h * 64 + f], s);
        (lr ? areff2 : aleff2)[h * 64 + k] = s;
        return;
    }
    i -= 1024;
    if (i < 1024) {  // aleff3 / areff3
        int lr = i >> 9; i &= 511;
        int h = i >> 6, k = i & 63;
        const float* a = lr ? ar3 : al3;
        float s = 0.f;
        for (int f = 0; f < 32; ++f)
            s = fmaf(W3[(size_t)k * 256 + h * 32 + f], a[h * 32 + f], s);
        (lr ? areff3 : aleff3)[h * 64 + k] = s;
        return;
    }
    i -= 1024;
    if (i < 16 * 512 * 4) {  // W4t2
        int kg = i >> 11, rem = i & 2047;
        int c = rem >> 2, j = rem & 3;
        W4t2[i] = W2[(size_t)(kg * 4 + j) * 512 + c];
        return;
    }
    i -= 16 * 512 * 4;
    if (i < 16384) {  // wfhi / wflo
        int plane = i >> 13;
        int rem = i & 8191;
        int j2 = rem & 3, l = (rem >> 2) & 63;
        int ks = (rem >> 8) & 1, nt = (rem >> 9) & 1, h = (rem >> 10) & 7;
        int col = h * 32 + nt * 16 + (l & 15);
        int kb = ks * 32 + (l >> 4) * 8 + 2 * j2;
        unsigned parts[2];
        #pragma unroll
        for (int q = 0; q < 2; ++q) {
            float w = W3[(size_t)(kb + q) * 256 + col];
            unsigned short hi = f2bf(w);
            parts[q] = plane ? (unsigned)f2bf(w - bf2f(hi)) : (unsigned)hi;
        }
        unsigned word = parts[0] | (parts[1] << 16);
        (plane ? wflo : wfhi)[rem] = word;
    }
}

// ---------------- single-block CSR build: hist + scan + scatter + stable-order sort ------
__global__ __launch_bounds__(1024) void csr_build_kernel(
    const int* __restrict__ dst, const int* __restrict__ src,
    int* __restrict__ row_ptr, int* __restrict__ csr_src) {
    __shared__ int cnt[N_NODES + 1];
    __shared__ int rp[N_NODES + 1];
    __shared__ int eid[N_EDGES];
    __shared__ int part[1024];
    int t = threadIdx.x;
    for (int i = t; i <= N_NODES; i += 1024) cnt[i] = 0;
    __syncthreads();
    for (int e = t; e < N_EDGES; e += 1024) atomicAdd(&cnt[dst[e]], 1);
    __syncthreads();
    int base = t * 2;
    int v0 = (base < N_NODES) ? cnt[base] : 0;
    int v1 = (base + 1 < N_NODES) ? cnt[base + 1] : 0;
    part[t] = v0 + v1;
    __syncthreads();
    if (t == 0) {
        int a = 0;
        for (int i = 0; i < 1024; ++i) { int v = part[i]; part[i] = a; a += v; }
        rp[N_NODES] = a;
    }
    __syncthreads();
    if (base < N_NODES) rp[base] = part[t];
    if (base + 1 < N_NODES) rp[base + 1] = part[t] + v0;
    __syncthreads();
    for (int i = t; i <= N_NODES; i += 1024) row_ptr[i] = rp[i];
    for (int i = t; i <= N_NODES; i += 1024) cnt[i] = 0;   // reuse as cursor
    __syncthreads();
    for (int e = t; e < N_EDGES; e += 1024) {
        int d = dst[e];
        int pos = rp[d] + atomicAdd(&cnt[d], 1);
        eid[pos] = e;
    }
    __syncthreads();
    int wv = t >> 6, lane = t & 63;
    for (int nd = wv; nd < N_NODES; nd += 16) {
        int r0 = rp[nd], deg = rp[nd + 1] - r0;
        for (int b0 = 0; b0 < deg; b0 += 64) {
            int i = b0 + lane;
            int my = (i < deg) ? eid[r0 + i] : 0x7fffffff;
            int rank = 0;
            for (int j = 0; j < deg; ++j) {
                int oj = eid[r0 + j];
                rank += (oj < my) ? 1 : 0;
            }
            if (i < deg) csr_src[r0 + rank] = src[my];
        }
    }
}

// ---------------- f32 tiled GEMM (layer 1): 32x32 tiles (752 blocks) ----------

#define GM 32
#define GN 32
#define GK 32

__global__ __launch_bounds__(256) void gemm_f32(const float* __restrict__ A,
                                                const float* __restrict__ B,
                                                float* __restrict__ C,
                                                int M, int N, int K) {
    __shared__ float As[GK][GM + 2];
    __shared__ float Bs[GK][GN + 2];
    int t = threadIdx.x;
    int col0 = blockIdx.x * GN, row0 = blockIdx.y * GM;
    int tx = t & 15, ty = t >> 4;
    int am = t >> 3, ak = (t & 7) * 4;
    int bk = t >> 3, bn = (t & 7) * 4;
    float acc[2][2] = {};
    for (int k0 = 0; k0 < K; k0 += GK) {
        int gr = row0 + am;
        float4 av = (gr < M) ? *(const float4*)&A[(size_t)gr * K + k0 + ak]
                             : make_float4(0.f, 0.f, 0.f, 0.f);
        float4 bv = *(const float4*)&B[(size_t)(k0 + bk) * N + col0 + bn];
        __syncthreads();
        As[ak + 0][am] = av.x; As[ak + 1][am] = av.y;
        As[ak + 2][am] = av.z; As[ak + 3][am] = av.w;
        *(float4*)&Bs[bk][bn] = bv;
        __syncthreads();
        #pragma unroll
        for (int kk = 0; kk < GK; ++kk) {
            float2 a2 = *(const float2*)&As[kk][ty * 2];
            float2 b2 = *(const float2*)&Bs[kk][tx * 2];
            acc[0][0] = fmaf(a2.x, b2.x, acc[0][0]);
            acc[0][1] = fmaf(a2.x, b2.y, acc[0][1]);
            acc[1][0] = fmaf(a2.y, b2.x, acc[1][0]);
            acc[1][1] = fmaf(a2.y, b2.y, acc[1][1]);
        }
    }
    #pragma unroll
    for (int i = 0; i < 2; ++i) {
        int gr = row0 + ty * 2 + i;
        if (gr < M) {
            float2 v = make_float2(acc[i][0], acc[i][1]);
            *(float2*)&C[(size_t)gr * N + col0 + tx * 2] = v;
        }
    }
}

// ---------------- el/er kernels ----------------

__global__ void elr_feat_kernel(const float* __restrict__ feat, const float* __restrict__ al,
                                const float* __restrict__ ar, float* __restrict__ el,
                                float* __restrict__ er, int RH) {
    int idx = blockIdx.x * blockDim.x + threadIdx.x;
    if (idx >= RH) return;
    int h = idx & (HEADS - 1);
    const float* fp = feat + (size_t)idx * HIDDEN;
    float sl = 0.f, sr = 0.f;
    for (int f = 0; f < HIDDEN; ++f) {
        float v = fp[f];
        sl = fmaf(v, al[h * HIDDEN + f], sl);
        sr = fmaf(v, ar[h * HIDDEN + f], sr);
    }
    el[idx] = sl;
    er[idx] = sr;
}

__global__ void elr_row_kernel(const float* __restrict__ X, const float* __restrict__ alv,
                               const float* __restrict__ arv, float* __restrict__ el,
                               float* __restrict__ er, int R) {
    int r = blockIdx.x * blockDim.x + threadIdx.x;
    if (r >= R) return;
    const float4* x4 = (const float4*)(X + (size_t)r * 64);
    float sl[8] = {}, sr[8] = {};
    for (int kg = 0; kg < 16; ++kg) {
        float4 xv = x4[kg];
        #pragma unroll
        for (int h = 0; h < 8; ++h) {
            float4 a = *(const float4*)&alv[h * 64 + kg * 4];
            float4 b = *(const float4*)&arv[h * 64 + kg * 4];
            sl[h] = fmaf(xv.x, a.x, fmaf(xv.y, a.y, fmaf(xv.z, a.z, fmaf(xv.w, a.w, sl[h]))));
            sr[h] = fmaf(xv.x, b.x, fmaf(xv.y, b.y, fmaf(xv.z, b.z, fmaf(xv.w, b.w, sr[h]))));
        }
    }
    float* elp = el + (size_t)r * 8;
    float* erp = er + (size_t)r * 8;
    #pragma unroll
    for (int h = 0; h < 8; ++h) { elp[h] = sl[h]; erp[h] = sr[h]; }
}

__device__ __forceinline__ float gelu_exact(float v) {
    return 0.5f * v * (1.0f + erff(v * 0.70710678118654752440f));
}

// ---------------- layer-1 aggregation: wave per (node, head-pair), src in registers ----------
__global__ __launch_bounds__(256) void agg_l1(
    const float* __restrict__ feat, const float* __restrict__ el, const float* __restrict__ er,
    const float* __restrict__ bias, const int* __restrict__ row_ptr,
    const int* __restrict__ csr_src, float* __restrict__ out) {
    int n = blockIdx.x;
    int t = threadIdx.x, wv = t >> 6, lane = t & 63;
    int h0 = 2 * wv;
    int r0 = row_ptr[n], deg = row_ptr[n + 1] - r0;
    float2 erv = *(const float2*)&er[n * 8 + h0];
    float den0 = 0.f, den1 = 0.f, a0 = 0.f, a1 = 0.f;
    for (int c0 = 0; c0 < deg; c0 += 64) {
        int cnt = min(deg - c0, 64);
        int src_r = (lane < cnt) ? csr_src[r0 + c0 + lane] : 0;
        auto do_edge = [&](int s) {
            float2 elv = *(const float2*)&el[s * 8 + h0];
            float x0 = feat[((size_t)s * 8 + h0) * 64 + lane];
            float x1 = feat[((size_t)s * 8 + h0 + 1) * 64 + lane];
            float e0 = elv.x + erv.x; e0 = e0 > 0.f ? e0 : 0.2f * e0;
            float e1 = elv.y + erv.y; e1 = e1 > 0.f ? e1 : 0.2f * e1;
            float w0 = __expf(e0), w1 = __expf(e1);
            den0 += w0; den1 += w1;
            a0 = fmaf(w0, x0, a0);
            a1 = fmaf(w1, x1, a1);
        };
        int i = 0;
        for (; i + 2 <= cnt; i += 2) {
            int s0 = __builtin_amdgcn_readlane(src_r, i);
            int s1 = __builtin_amdgcn_readlane(src_r, i + 1);
            do_edge(s0);
            do_edge(s1);
        }
        if (i < cnt) do_edge(__builtin_amdgcn_readlane(src_r, i));
    }
    float i0 = deg ? 1.f / den0 : 0.f;
    float i1 = deg ? 1.f / den1 : 0.f;
    float v0 = a0 * i0 + bias[h0 * 64 + lane];
    float v1 = a1 * i1 + bias[(h0 + 1) * 64 + lane];
    out[((size_t)n * 8 + h0) * 64 + lane] = gelu_exact(v0);
    out[((size_t)n * 8 + h0 + 1) * 64 + lane] = gelu_exact(v1);
}

// ---------------- layer 2: LDS-staged weights + single-pass transform (r11 version) ----------
__global__ __launch_bounds__(256, 4) void agg_fused5(
    const float* __restrict__ X,     // h1 [N*8, 64]
    const float* __restrict__ el, const float* __restrict__ er,  // [N*8, 8]
    const float* __restrict__ W4t,   // [16][512][4]
    const float* __restrict__ bias,  // [512]
    const int* __restrict__ row_ptr, const int* __restrict__ csr_src,
    float* __restrict__ out)         // h2 [N*8, 512]
{
    constexpr int TOT = 512;
    constexpr int PTS = 68;
    constexpr int CHUNK = 64;

    int n = blockIdx.x;
    int r0 = row_ptr[n], deg = row_ptr[n + 1] - r0;
    int t = threadIdx.x, wv = t >> 6, lane = t & 63;

    __shared__ float inv_s[64];
    __shared__ float acc_s[8][8][68];
    __shared__ float wp_lds[64 * PTS];

    float agg0[8], agg1[8];
    #pragma unroll
    for (int h = 0; h < 8; ++h) { agg0[h] = 0.f; agg1[h] = 0.f; }
    float den = 0.f;

    int elbase_n = n * 8 * 8;
    int pA = wv * 2;
    float erv_t = er[elbase_n + lane];

    for (int c0 = 0; c0 < deg; c0 += CHUNK) {
        int cnt = min(deg - c0, CHUNK);
        int src_r = (lane < cnt) ? csr_src[r0 + c0 + lane] : 0;
        __syncthreads();
        for (int j = t; j < cnt * 64; j += 256) {
            int i = j >> 6;
            int s = __builtin_amdgcn_readlane(src_r, i);
            float e = el[(s * 8) * 8 + lane] + erv_t;
            e = e > 0.f ? e : 0.2f * e;
            wp_lds[i * 64 + lane] = __expf(e);
        }
        __syncthreads();
        if (t < 64) {
            for (int i = 0; i < cnt; ++i) den += wp_lds[i * 64 + t];
        }
        auto edge_fma = [&](int i) {
            int s = __builtin_amdgcn_readlane(src_r, i);
            const float* wp = &wp_lds[i * 64 + wv * 16];
            float4 w0 = *(const float4*)wp;
            float4 w1 = *(const float4*)(wp + 4);
            float4 w2 = *(const float4*)(wp + 8);
            float4 w3 = *(const float4*)(wp + 12);
            int xb = (s * 8 + pA) * 64 + lane;
            float xv0 = X[xb];
            float xv1 = X[xb + 64];
            agg0[0] = fmaf(w0.x, xv0, agg0[0]);
            agg0[1] = fmaf(w0.y, xv0, agg0[1]);
            agg0[2] = fmaf(w0.z, xv0, agg0[2]);
            agg0[3] = fmaf(w0.w, xv0, agg0[3]);
            agg0[4] = fmaf(w1.x, xv0, agg0[4]);
            agg0[5] = fmaf(w1.y, xv0, agg0[5]);
            agg0[6] = fmaf(w1.z, xv0, agg0[6]);
            agg0[7] = fmaf(w1.w, xv0, agg0[7]);
            agg1[0] = fmaf(w2.x, xv1, agg1[0]);
            agg1[1] = fmaf(w2.y, xv1, agg1[1]);
            agg1[2] = fmaf(w2.z, xv1, agg1[2]);
            agg1[3] = fmaf(w2.w, xv1, agg1[3]);
            agg1[4] = fmaf(w3.x, xv1, agg1[4]);
            agg1[5] = fmaf(w3.y, xv1, agg1[5]);
            agg1[6] = fmaf(w3.z, xv1, agg1[6]);
            agg1[7] = fmaf(w3.w, xv1, agg1[7]);
        };
        int i = 0;
        for (; i + 2 <= cnt; i += 2) { edge_fma(i); edge_fma(i + 1); }
        if (i < cnt) edge_fma(i);
    }
    if (t < 64) inv_s[t] = deg ? 1.f / den : 0.f;
    __syncthreads();
    {
        int pl0 = wv * 2;
        #pragma unroll
        for (int h = 0; h < 8; ++h) {
            acc_s[pl0][h][lane] = agg0[h] * inv_s[pl0 * 8 + h];
            acc_s[pl0 + 1][h][lane] = agg1[h] * inv_s[pl0 * 8 + 8 + h];
        }
    }
    __syncthreads();

    // Phase T: thread = (h = t>>5, ft = t&31); 2 outputs f0 = ft*2, all 16 kg.
    {
        int h = t >> 5, ft = t & 31;
        int f0 = ft * 2;
        float part[8][2];
        #pragma unroll
        for (int pl = 0; pl < 8; ++pl) { part[pl][0] = 0.f; part[pl][1] = 0.f; }
        #pragma unroll
        for (int kg = 0; kg < 16; ++kg) {
            float4 wr0 = *(const float4*)&W4t[(size_t)(kg * TOT + h * 64 + f0 + 0) * 4];
            float4 wr1 = *(const float4*)&W4t[(size_t)(kg * TOT + h * 64 + f0 + 1) * 4];
            #pragma unroll
            for (int pl = 0; pl < 8; ++pl) {
                float4 a4 = *(const float4*)&acc_s[pl][h][kg * 4];
                part[pl][0] = fmaf(a4.x, wr0.x, fmaf(a4.y, wr0.y,
                              fmaf(a4.z, wr0.z, fmaf(a4.w, wr0.w, part[pl][0]))));
                part[pl][1] = fmaf(a4.x, wr1.x, fmaf(a4.y, wr1.y,
                              fmaf(a4.z, wr1.z, fmaf(a4.w, wr1.w, part[pl][1]))));
            }
        }
        __syncthreads();
        #pragma unroll
        for (int pl = 0; pl < 8; ++pl)
            *(float2*)&wp_lds[(pl * 8 + h) * PTS + f0] = make_float2(part[pl][0], part[pl][1]);
    }
    __syncthreads();

    // Phase R: bias + gelu + coalesced float4 store
    {
        for (int q = t; q < 1024; q += 256) {
            int pl = q >> 7, rem = q & 127;
            int h = rem >> 4, fq = rem & 15;
            int f0 = fq * 4;
            float4 acc4 = *(const float4*)&wp_lds[(pl * 8 + h) * PTS + f0];
            float4 b4 = *(const float4*)&bias[h * 64 + f0];
            acc4.x = gelu_exact(acc4.x + b4.x);
            acc4.y = gelu_exact(acc4.y + b4.y);
            acc4.z = gelu_exact(acc4.z + b4.z);
            acc4.w = gelu_exact(acc4.w + b4.w);
            *(float4*)&out[(size_t)(n * 8 + pl) * TOT + h * 64 + f0] = acc4;
        }
    }
}

// ---------------- layer 3: register-src aggregation + split-h MFMA transform ----------------
// 6000 blocks, 6 blocks/CU; nontemporal out stores.
__global__ __launch_bounds__(256, 6) void agg_mfma6(
    const float* __restrict__ X,        // h2 [N*64, 64]
    const float* __restrict__ el, const float* __restrict__ er,  // [N*64, 8]
    const unsigned* __restrict__ wfhi, const unsigned* __restrict__ wflo,
    const float* __restrict__ bias,     // [256]
    const int* __restrict__ row_ptr, const int* __restrict__ csr_src,
    float* __restrict__ out)            // [N*64, 256]
{
    int b = blockIdx.x;                  // 6000 = 1500 n * 4 pg
    int n = b >> 2, pg = b & 3;
    int p0 = pg * 16;
    int r0 = row_ptr[n], deg = row_ptr[n + 1] - r0;
    int t = threadIdx.x, wv = t >> 6, lane = t & 63;
    int pA = p0 + wv * 4;

    __shared__ unsigned accH[4][16][68];   // [h in round][pl][k] packed bf16 hi|lo

    int c = lane & 31;                     // (q,h) = (c>>3, c&7)
    float erv = er[(n * 64 + pA) * 8 + c];

    float agg[4][8];
    #pragma unroll
    for (int q = 0; q < 4; ++q)
        #pragma unroll
        for (int h = 0; h < 8; ++h) agg[q][h] = 0.f;
    float den_half = 0.f;

    for (int c0 = 0; c0 < deg; c0 += 64) {
        int cnt = min(deg - c0, 64);
        int src_r = (lane < cnt) ? csr_src[r0 + c0 + lane] : 0;
        for (int it = 0; it < cnt; it += 4) {
            int i1 = min(it + 1, cnt - 1), i2 = min(it + 2, cnt - 1), i3 = min(it + 3, cnt - 1);
            int s0 = __builtin_amdgcn_readlane(src_r, it);
            int s1 = __builtin_amdgcn_readlane(src_r, i1);
            int s2 = __builtin_amdgcn_readlane(src_r, i2);
            int s3 = __builtin_amdgcn_readlane(src_r, i3);
            bool v1 = it + 1 < cnt, v2 = it + 2 < cnt, v3 = it + 3 < cnt;
            int sA = (lane < 32) ? s0 : s1;
            int sB = (lane < 32) ? s2 : s3;
            float eA = el[(sA * 64 + pA) * 8 + c] + erv;
            float eB = el[(sB * 64 + pA) * 8 + c] + erv;
            eA = eA > 0.f ? eA : 0.2f * eA;
            eB = eB > 0.f ? eB : 0.2f * eB;
            if (lane >= 32 && !v1) eA = -1e30f;
            if (lane < 32 && !v2) eB = -1e30f;
            if (lane >= 32 && !v3) eB = -1e30f;
            float wA = __expf(eA), wB = __expf(eB);
            den_half += wA + wB;
            int xb0 = (s0 * 64 + pA) * 64 + lane;
            int xb1 = (s1 * 64 + pA) * 64 + lane;
            int xb2 = (s2 * 64 + pA) * 64 + lane;
            int xb3 = (s3 * 64 + pA) * 64 + lane;
            float x0[4], x1[4], x2[4], x3[4];
            #pragma unroll
            for (int q = 0; q < 4; ++q) x0[q] = X[xb0 + q * 64];
            #pragma unroll
            for (int q = 0; q < 4; ++q) x1[q] = X[xb1 + q * 64];
            #pragma unroll
            for (int q = 0; q < 4; ++q) x2[q] = X[xb2 + q * 64];
            #pragma unroll
            for (int q = 0; q < 4; ++q) x3[q] = X[xb3 + q * 64];
            #pragma unroll
            for (int q = 0; q < 4; ++q) {
                #pragma unroll
                for (int h = 0; h < 8; ++h) {
                    agg[q][h] = fmaf(rdlanef(wA, q * 8 + h), x0[q], agg[q][h]);
                    agg[q][h] = fmaf(rdlanef(wA, 32 + q * 8 + h), x1[q], agg[q][h]);
                    agg[q][h] = fmaf(rdlanef(wB, q * 8 + h), x2[q], agg[q][h]);
                    agg[q][h] = fmaf(rdlanef(wB, 32 + q * 8 + h), x3[q], agg[q][h]);
                }
            }
        }
    }
    float den = den_half + __shfl(den_half, lane ^ 32);
    float inv = deg ? 1.f / den : 0.f;

    int m16 = lane & 15, g = lane >> 4;
    #pragma unroll
    for (int r = 0; r < 2; ++r) {
        if (r) __syncthreads();
        #pragma unroll
        for (int q = 0; q < 4; ++q) {
            int pl = wv * 4 + q;
            #pragma unroll
            for (int hh = 0; hh < 4; ++hh) {
                int h = 4 * r + hh;
                float iv = rdlanef(inv, q * 8 + h);
                accH[hh][pl][lane] = packbf(agg[q][h] * iv);
            }
        }
        __syncthreads();
        int h = 4 * r + wv;
        bf16x8 a_hi[2], a_lo[2];
        #pragma unroll
        for (int ks = 0; ks < 2; ++ks) {
            const unsigned* ap = &accH[wv][m16][ks * 32 + g * 8];
            uint4 q0 = *(const uint4*)ap;
            uint4 q1 = *(const uint4*)(ap + 4);
            a_hi[ks][0] = (short)(q0.x & 0xffffu); a_lo[ks][0] = (short)(q0.x >> 16);
            a_hi[ks][1] = (short)(q0.y & 0xffffu); a_lo[ks][1] = (short)(q0.y >> 16);
            a_hi[ks][2] = (short)(q0.z & 0xffffu); a_lo[ks][2] = (short)(q0.z >> 16);
            a_hi[ks][3] = (short)(q0.w & 0xffffu); a_lo[ks][3] = (short)(q0.w >> 16);
            a_hi[ks][4] = (short)(q1.x & 0xffffu); a_lo[ks][4] = (short)(q1.x >> 16);
            a_hi[ks][5] = (short)(q1.y & 0xffffu); a_lo[ks][5] = (short)(q1.y >> 16);
            a_hi[ks][6] = (short)(q1.z & 0xffffu); a_lo[ks][6] = (short)(q1.z >> 16);
            a_hi[ks][7] = (short)(q1.w & 0xffffu); a_lo[ks][7] = (short)(q1.w >> 16);
        }
        #pragma unroll
        for (int nt = 0; nt < 2; ++nt) {
            f32x4 D = {0.f, 0.f, 0.f, 0.f};
            #pragma unroll
            for (int ks = 0; ks < 2; ++ks) {
                size_t fb = (size_t)(((h * 2 + nt) * 2 + ks) * 64 + lane) * 4;
                bf16x8 b_hi = *(const bf16x8*)&wfhi[fb];
                bf16x8 b_lo = *(const bf16x8*)&wflo[fb];
                D = __builtin_amdgcn_mfma_f32_16x16x32_bf16(a_hi[ks], b_hi, D, 0, 0, 0);
                D = __builtin_amdgcn_mfma_f32_16x16x32_bf16(a_hi[ks], b_lo, D, 0, 0, 0);
                D = __builtin_amdgcn_mfma_f32_16x16x32_bf16(a_lo[ks], b_hi, D, 0, 0, 0);
            }
            float bv = bias[h * 32 + nt * 16 + m16];
            size_t ob = ((size_t)(n * 64) + p0 + g * 4) * 256 + h * 32 + nt * 16 + m16;
            __builtin_nontemporal_store(D[0] + bv, &out[ob]);
            __builtin_nontemporal_store(D[1] + bv, &out[ob + 256]);
            __builtin_nontemporal_store(D[2] + bv, &out[ob + 512]);
            __builtin_nontemporal_store(D[3] + bv, &out[ob + 768]);
        }
    }
}

// ---------------- launch ----------------

extern "C" void kernel_launch(void* const* d_in, const int* in_sizes, int n_in,
                              void* d_out, int out_size, void* d_ws, size_t ws_size,
                              hipStream_t stream) {
    const float* node = (const float*)d_in[0];
    const int* src = (const int*)d_in[1];
    const int* dst = (const int*)d_in[2];
    const float* W1 = (const float*)d_in[3];
    const float* al1 = (const float*)d_in[4];
    const float* ar1 = (const float*)d_in[5];
    const float* b1 = (const float*)d_in[6];
    const float* W2 = (const float*)d_in[7];
    const float* al2 = (const float*)d_in[8];
    const float* ar2 = (const float*)d_in[9];
    const float* b2 = (const float*)d_in[10];
    const float* W3 = (const float*)d_in[11];
    const float* al3 = (const float*)d_in[12];
    const float* ar3 = (const float*)d_in[13];
    const float* b3 = (const float*)d_in[14];
    float* out = (float*)d_out;

    char* ws = (char*)d_ws;
    size_t off = 0;
    auto alloc = [&](size_t nb) -> char* {
        char* q = ws + off;
        off += (nb + 255) & ~(size_t)255;
        return q;
    };
    int* row_ptr  = (int*)alloc((N_NODES + 1) * sizeof(int));
    int* csr_src  = (int*)alloc(N_EDGES * sizeof(int));
    float* feat1  = (float*)alloc((size_t)N_NODES * 8 * 64 * 4);
    float* el1    = (float*)alloc((size_t)N_NODES * 8 * 4);
    float* er1    = (float*)alloc((size_t)N_NODES * 8 * 4);
    float* h1     = (float*)alloc((size_t)N_NODES * 8 * 64 * 4);
    float* aleff2 = (float*)alloc(8 * 64 * 4);
    float* areff2 = (float*)alloc(8 * 64 * 4);
    float* el2    = (float*)alloc((size_t)N_NODES * 8 * 8 * 4);
    float* er2    = (float*)alloc((size_t)N_NODES * 8 * 8 * 4);
    float* h2     = (float*)alloc((size_t)N_NODES * 64 * 64 * 4);
    float* aleff3 = (float*)alloc(8 * 64 * 4);
    float* areff3 = (float*)alloc(8 * 64 * 4);
    float* el3    = (float*)alloc((size_t)N_NODES * 64 * 8 * 4);
    float* er3    = (float*)alloc((size_t)N_NODES * 64 * 8 * 4);
    float* W4t2   = (float*)alloc((size_t)16 * 512 * 4 * 4);
    unsigned* wfhi = (unsigned*)alloc((size_t)8192 * 4);
    unsigned* wflo = (unsigned*)alloc((size_t)8192 * 4);

    const int PREP_T = 1024 + 1024 + 16 * 512 * 4 + 16384;
    prep_kernel<<<(PREP_T + 255) / 256, 256, 0, stream>>>(
        W2, al2, ar2, W3, al3, ar3, aleff2, areff2, aleff3, areff3, W4t2, wfhi, wflo);

    csr_build_kernel<<<1, 1024, 0, stream>>>(dst, src, row_ptr, csr_src);

    // ---- layer 1 ----
    dim3 g1((512 + GN - 1) / GN, (N_NODES + GM - 1) / GM);
    gemm_f32<<<g1, 256, 0, stream>>>(node, W1, feat1, N_NODES, 512, IN_FEAT);
    elr_feat_kernel<<<(N_NODES * 8 + 255) / 256, 256, 0, stream>>>(feat1, al1, ar1, el1, er1, N_NODES * 8);
    agg_l1<<<N_NODES, 256, 0, stream>>>(feat1, el1, er1, b1, row_ptr, csr_src, h1);

    // ---- layer 2 ----
    elr_row_kernel<<<(N_NODES * 8 + 255) / 256, 256, 0, stream>>>(h1, aleff2, areff2, el2, er2, N_NODES * 8);
    agg_fused5<<<N_NODES, 256, 0, stream>>>(h1, el2, er2, W4t2, b2, row_ptr, csr_src, h2);

    // ---- layer 3 ----
    elr_row_kernel<<<(N_NODES * 64 + 255) / 256, 256, 0, stream>>>(h2, aleff3, areff3, el3, er3, N_NODES * 64);
    agg_mfma6<<<N_NODES * 4, 256, 0, stream>>>(h2, el3, er3, wfhi, wflo, b3, row_ptr, csr_src, out);
}

// Round 14
// 161.219 us; speedup vs baseline: 1.4369x; 1.3801x over previous
//
#include <hip/hip_runtime.h>
#include <math.h>

#define N_NODES 1500
#define N_EDGES 12000
#define IN_FEAT 512
#define HIDDEN 64
#define OUT_FEAT 32
#define HEADS 8

typedef short bf16x8 __attribute__((ext_vector_type(8)));
typedef float f32x4 __attribute__((ext_vector_type(4)));

__device__ __forceinline__ unsigned short f2bf(float f) {
    unsigned u = __float_as_uint(f);
    u += 0x7fff + ((u >> 16) & 1);   // RNE
    return (unsigned short)(u >> 16);
}
__device__ __forceinline__ float bf2f(unsigned short b) {
    return __uint_as_float(((unsigned)b) << 16);
}
__device__ __forceinline__ unsigned packbf(float a) {
    unsigned short hi = f2bf(a);
    unsigned short lo = f2bf(a - bf2f(hi));
    return (unsigned)hi | ((unsigned)lo << 16);
}
__device__ __forceinline__ float rdlanef(float v, int c) {
    return __uint_as_float(__builtin_amdgcn_readlane(__float_as_uint(v), c));
}

// ---------------- prep: zeros + att-eff vectors + W2 reshuffle + W3 hi/lo frags ----
__global__ void prep_kernel(const float* __restrict__ W2, const float* __restrict__ al2,
                            const float* __restrict__ ar2,
                            const float* __restrict__ W3, const float* __restrict__ al3,
                            const float* __restrict__ ar3,
                            float* __restrict__ aleff2, float* __restrict__ areff2,
                            float* __restrict__ aleff3, float* __restrict__ areff3,
                            float* __restrict__ W4t2,
                            unsigned* __restrict__ wfhi, unsigned* __restrict__ wflo,
                            int* __restrict__ counts, int* __restrict__ cursor) {
    int i = blockIdx.x * blockDim.x + threadIdx.x;
    if (i < 1536) {
        if (i < N_NODES + 1) counts[i] = 0;
        return;
    }
    i -= 1536;
    if (i < 1536) {
        if (i < N_NODES) cursor[i] = 0;
        return;
    }
    i -= 1536;
    if (i < 1024) {  // aleff2 / areff2
        int lr = i >> 9; i &= 511;
        int h = i >> 6, k = i & 63;
        const float* a = lr ? ar2 : al2;
        float s = 0.f;
        for (int f = 0; f < 64; ++f)
            s = fmaf(W2[(size_t)k * 512 + h * 64 + f], a[h * 64 + f], s);
        (lr ? areff2 : aleff2)[h * 64 + k] = s;
        return;
    }
    i -= 1024;
    if (i < 1024) {  // aleff3 / areff3
        int lr = i >> 9; i &= 511;
        int h = i >> 6, k = i & 63;
        const float* a = lr ? ar3 : al3;
        float s = 0.f;
        for (int f = 0; f < 32; ++f)
            s = fmaf(W3[(size_t)k * 256 + h * 32 + f], a[h * 32 + f], s);
        (lr ? areff3 : aleff3)[h * 64 + k] = s;
        return;
    }
    i -= 1024;
    if (i < 16 * 512 * 4) {  // W4t2
        int kg = i >> 11, rem = i & 2047;
        int c = rem >> 2, j = rem & 3;
        W4t2[i] = W2[(size_t)(kg * 4 + j) * 512 + c];
        return;
    }
    i -= 16 * 512 * 4;
    if (i < 16384) {  // wfhi / wflo
        int plane = i >> 13;
        int rem = i & 8191;
        int j2 = rem & 3, l = (rem >> 2) & 63;
        int ks = (rem >> 8) & 1, nt = (rem >> 9) & 1, h = (rem >> 10) & 7;
        int col = h * 32 + nt * 16 + (l & 15);
        int kb = ks * 32 + (l >> 4) * 8 + 2 * j2;
        unsigned parts[2];
        #pragma unroll
        for (int q = 0; q < 2; ++q) {
            float w = W3[(size_t)(kb + q) * 256 + col];
            unsigned short hi = f2bf(w);
            parts[q] = plane ? (unsigned)f2bf(w - bf2f(hi)) : (unsigned)hi;
        }
        unsigned word = parts[0] | (parts[1] << 16);
        (plane ? wflo : wfhi)[rem] = word;
    }
}

__global__ void hist_kernel(const int* __restrict__ dst, int* __restrict__ counts) {
    int e = blockIdx.x * blockDim.x + threadIdx.x;
    if (e < N_EDGES) atomicAdd(&counts[dst[e]], 1);
}

__global__ void scan_kernel(const int* __restrict__ counts, int* __restrict__ row_ptr) {
    __shared__ int part[256];
    int t = threadIdx.x;
    const int CH = (N_NODES + 255) / 256;
    int base = t * CH;
    int loc[8];
    int s = 0;
    for (int i = 0; i < CH; ++i) {
        int idx = base + i;
        int v = (idx < N_NODES) ? counts[idx] : 0;
        loc[i] = s;
        s += v;
    }
    part[t] = s;
    __syncthreads();
    if (t == 0) {
        int a = 0;
        for (int i = 0; i < 256; ++i) { int v = part[i]; part[i] = a; a += v; }
        row_ptr[N_NODES] = a;
    }
    __syncthreads();
    int p0 = part[t];
    for (int i = 0; i < CH; ++i) {
        int idx = base + i;
        if (idx < N_NODES) row_ptr[idx] = p0 + loc[i];
    }
}

__global__ void scatter_kernel(const int* __restrict__ dst, const int* __restrict__ row_ptr,
                               int* __restrict__ cursor, int* __restrict__ tmp_eid) {
    int e = blockIdx.x * blockDim.x + threadIdx.x;
    if (e < N_EDGES) {
        int d = dst[e];
        int pos = row_ptr[d] + atomicAdd(&cursor[d], 1);
        tmp_eid[pos] = e;
    }
}

// per-node sort by edge id -> deterministic stable order
__global__ void sort_csr_kernel(const int* __restrict__ row_ptr, const int* __restrict__ tmp_eid,
                                const int* __restrict__ src, int* __restrict__ csr_src) {
    int wid = (blockIdx.x * blockDim.x + threadIdx.x) >> 6;
    int lane = threadIdx.x & 63;
    if (wid >= N_NODES) return;
    int r0 = row_ptr[wid], deg = row_ptr[wid + 1] - r0;
    for (int base = 0; base < deg; base += 64) {
        int i = base + lane;
        int my = (i < deg) ? tmp_eid[r0 + i] : 0x7fffffff;
        int rank = 0;
        for (int b2 = 0; b2 < deg; b2 += 64) {
            int other = (b2 + lane < deg) ? tmp_eid[r0 + b2 + lane] : 0x7fffffff;
            int cnt2 = min(deg - b2, 64);
            for (int j = 0; j < cnt2; ++j) {
                int oj = __shfl(other, j);
                rank += (oj < my) ? 1 : 0;
            }
        }
        if (i < deg) csr_src[r0 + rank] = src[my];
    }
}

// ---------------- f32 tiled GEMM (layer 1): 32x32 tiles (752 blocks) ----------

#define GM 32
#define GN 32
#define GK 32

__global__ __launch_bounds__(256) void gemm_f32(const float* __restrict__ A,
                                                const float* __restrict__ B,
                                                float* __restrict__ C,
                                                int M, int N, int K) {
    __shared__ float As[GK][GM + 2];
    __shared__ float Bs[GK][GN + 2];
    int t = threadIdx.x;
    int col0 = blockIdx.x * GN, row0 = blockIdx.y * GM;
    int tx = t & 15, ty = t >> 4;
    int am = t >> 3, ak = (t & 7) * 4;
    int bk = t >> 3, bn = (t & 7) * 4;
    float acc[2][2] = {};
    for (int k0 = 0; k0 < K; k0 += GK) {
        int gr = row0 + am;
        float4 av = (gr < M) ? *(const float4*)&A[(size_t)gr * K + k0 + ak]
                             : make_float4(0.f, 0.f, 0.f, 0.f);
        float4 bv = *(const float4*)&B[(size_t)(k0 + bk) * N + col0 + bn];
        __syncthreads();
        As[ak + 0][am] = av.x; As[ak + 1][am] = av.y;
        As[ak + 2][am] = av.z; As[ak + 3][am] = av.w;
        *(float4*)&Bs[bk][bn] = bv;
        __syncthreads();
        #pragma unroll
        for (int kk = 0; kk < GK; ++kk) {
            float2 a2 = *(const float2*)&As[kk][ty * 2];
            float2 b2 = *(const float2*)&Bs[kk][tx * 2];
            acc[0][0] = fmaf(a2.x, b2.x, acc[0][0]);
            acc[0][1] = fmaf(a2.x, b2.y, acc[0][1]);
            acc[1][0] = fmaf(a2.y, b2.x, acc[1][0]);
            acc[1][1] = fmaf(a2.y, b2.y, acc[1][1]);
        }
    }
    #pragma unroll
    for (int i = 0; i < 2; ++i) {
        int gr = row0 + ty * 2 + i;
        if (gr < M) {
            float2 v = make_float2(acc[i][0], acc[i][1]);
            *(float2*)&C[(size_t)gr * N + col0 + tx * 2] = v;
        }
    }
}

// ---------------- el/er kernels ----------------

__global__ void elr_feat_kernel(const float* __restrict__ feat, const float* __restrict__ al,
                                const float* __restrict__ ar, float* __restrict__ el,
                                float* __restrict__ er, int RH) {
    int idx = blockIdx.x * blockDim.x + threadIdx.x;
    if (idx >= RH) return;
    int h = idx & (HEADS - 1);
    const float* fp = feat + (size_t)idx * HIDDEN;
    float sl = 0.f, sr = 0.f;
    for (int f = 0; f < HIDDEN; ++f) {
        float v = fp[f];
        sl = fmaf(v, al[h * HIDDEN + f], sl);
        sr = fmaf(v, ar[h * HIDDEN + f], sr);
    }
    el[idx] = sl;
    er[idx] = sr;
}

__global__ void elr_row_kernel(const float* __restrict__ X, const float* __restrict__ alv,
                               const float* __restrict__ arv, float* __restrict__ el,
                               float* __restrict__ er, int R) {
    int r = blockIdx.x * blockDim.x + threadIdx.x;
    if (r >= R) return;
    const float4* x4 = (const float4*)(X + (size_t)r * 64);
    float sl[8] = {}, sr[8] = {};
    for (int kg = 0; kg < 16; ++kg) {
        float4 xv = x4[kg];
        #pragma unroll
        for (int h = 0; h < 8; ++h) {
            float4 a = *(const float4*)&alv[h * 64 + kg * 4];
            float4 b = *(const float4*)&arv[h * 64 + kg * 4];
            sl[h] = fmaf(xv.x, a.x, fmaf(xv.y, a.y, fmaf(xv.z, a.z, fmaf(xv.w, a.w, sl[h]))));
            sr[h] = fmaf(xv.x, b.x, fmaf(xv.y, b.y, fmaf(xv.z, b.z, fmaf(xv.w, b.w, sr[h]))));
        }
    }
    float* elp = el + (size_t)r * 8;
    float* erp = er + (size_t)r * 8;
    #pragma unroll
    for (int h = 0; h < 8; ++h) { elp[h] = sl[h]; erp[h] = sr[h]; }
}

__device__ __forceinline__ float gelu_exact(float v) {
    return 0.5f * v * (1.0f + erff(v * 0.70710678118654752440f));
}

// ---------------- layer-1 aggregation: wave per (node, head-pair), src in registers ----------
__global__ __launch_bounds__(256) void agg_l1(
    const float* __restrict__ feat, const float* __restrict__ el, const float* __restrict__ er,
    const float* __restrict__ bias, const int* __restrict__ row_ptr,
    const int* __restrict__ csr_src, float* __restrict__ out) {
    int n = blockIdx.x;
    int t = threadIdx.x, wv = t >> 6, lane = t & 63;
    int h0 = 2 * wv;
    int r0 = row_ptr[n], deg = row_ptr[n + 1] - r0;
    float2 erv = *(const float2*)&er[n * 8 + h0];
    float den0 = 0.f, den1 = 0.f, a0 = 0.f, a1 = 0.f;
    for (int c0 = 0; c0 < deg; c0 += 64) {
        int cnt = min(deg - c0, 64);
        int src_r = (lane < cnt) ? csr_src[r0 + c0 + lane] : 0;
        auto do_edge = [&](int s) {
            float2 elv = *(const float2*)&el[s * 8 + h0];
            float x0 = feat[((size_t)s * 8 + h0) * 64 + lane];
            float x1 = feat[((size_t)s * 8 + h0 + 1) * 64 + lane];
            float e0 = elv.x + erv.x; e0 = e0 > 0.f ? e0 : 0.2f * e0;
            float e1 = elv.y + erv.y; e1 = e1 > 0.f ? e1 : 0.2f * e1;
            float w0 = __expf(e0), w1 = __expf(e1);
            den0 += w0; den1 += w1;
            a0 = fmaf(w0, x0, a0);
            a1 = fmaf(w1, x1, a1);
        };
        int i = 0;
        for (; i + 2 <= cnt; i += 2) {
            int s0 = __builtin_amdgcn_readlane(src_r, i);
            int s1 = __builtin_amdgcn_readlane(src_r, i + 1);
            do_edge(s0);
            do_edge(s1);
        }
        if (i < cnt) do_edge(__builtin_amdgcn_readlane(src_r, i));
    }
    float i0 = deg ? 1.f / den0 : 0.f;
    float i1 = deg ? 1.f / den1 : 0.f;
    float v0 = a0 * i0 + bias[h0 * 64 + lane];
    float v1 = a1 * i1 + bias[(h0 + 1) * 64 + lane];
    out[((size_t)n * 8 + h0) * 64 + lane] = gelu_exact(v0);
    out[((size_t)n * 8 + h0 + 1) * 64 + lane] = gelu_exact(v1);
}

// ---------------- layer 2: LDS-staged weights + single-pass transform ----------
__global__ __launch_bounds__(256, 4) void agg_fused5(
    const float* __restrict__ X,     // h1 [N*8, 64]
    const float* __restrict__ el, const float* __restrict__ er,  // [N*8, 8]
    const float* __restrict__ W4t,   // [16][512][4]
    const float* __restrict__ bias,  // [512]
    const int* __restrict__ row_ptr, const int* __restrict__ csr_src,
    float* __restrict__ out)         // h2 [N*8, 512]
{
    constexpr int TOT = 512;
    constexpr int PTS = 68;
    constexpr int CHUNK = 64;

    int n = blockIdx.x;
    int r0 = row_ptr[n], deg = row_ptr[n + 1] - r0;
    int t = threadIdx.x, wv = t >> 6, lane = t & 63;

    __shared__ float inv_s[64];
    __shared__ float acc_s[8][8][68];
    __shared__ float wp_lds[64 * PTS];

    float agg0[8], agg1[8];
    #pragma unroll
    for (int h = 0; h < 8; ++h) { agg0[h] = 0.f; agg1[h] = 0.f; }
    float den = 0.f;

    int elbase_n = n * 8 * 8;
    int pA = wv * 2;
    float erv_t = er[elbase_n + lane];

    for (int c0 = 0; c0 < deg; c0 += CHUNK) {
        int cnt = min(deg - c0, CHUNK);
        int src_r = (lane < cnt) ? csr_src[r0 + c0 + lane] : 0;
        __syncthreads();
        for (int j = t; j < cnt * 64; j += 256) {
            int i = j >> 6;
            int s = __builtin_amdgcn_readlane(src_r, i);
            float e = el[(s * 8) * 8 + lane] + erv_t;
            e = e > 0.f ? e : 0.2f * e;
            wp_lds[i * 64 + lane] = __expf(e);
        }
        __syncthreads();
        if (t < 64) {
            for (int i = 0; i < cnt; ++i) den += wp_lds[i * 64 + t];
        }
        auto edge_fma = [&](int i) {
            int s = __builtin_amdgcn_readlane(src_r, i);
            const float* wp = &wp_lds[i * 64 + wv * 16];
            float4 w0 = *(const float4*)wp;
            float4 w1 = *(const float4*)(wp + 4);
            float4 w2 = *(const float4*)(wp + 8);
            float4 w3 = *(const float4*)(wp + 12);
            int xb = (s * 8 + pA) * 64 + lane;
            float xv0 = X[xb];
            float xv1 = X[xb + 64];
            agg0[0] = fmaf(w0.x, xv0, agg0[0]);
            agg0[1] = fmaf(w0.y, xv0, agg0[1]);
            agg0[2] = fmaf(w0.z, xv0, agg0[2]);
            agg0[3] = fmaf(w0.w, xv0, agg0[3]);
            agg0[4] = fmaf(w1.x, xv0, agg0[4]);
            agg0[5] = fmaf(w1.y, xv0, agg0[5]);
            agg0[6] = fmaf(w1.z, xv0, agg0[6]);
            agg0[7] = fmaf(w1.w, xv0, agg0[7]);
            agg1[0] = fmaf(w2.x, xv1, agg1[0]);
            agg1[1] = fmaf(w2.y, xv1, agg1[1]);
            agg1[2] = fmaf(w2.z, xv1, agg1[2]);
            agg1[3] = fmaf(w2.w, xv1, agg1[3]);
            agg1[4] = fmaf(w3.x, xv1, agg1[4]);
            agg1[5] = fmaf(w3.y, xv1, agg1[5]);
            agg1[6] = fmaf(w3.z, xv1, agg1[6]);
            agg1[7] = fmaf(w3.w, xv1, agg1[7]);
        };
        int i = 0;
        for (; i + 2 <= cnt; i += 2) { edge_fma(i); edge_fma(i + 1); }
        if (i < cnt) edge_fma(i);
    }
    if (t < 64) inv_s[t] = deg ? 1.f / den : 0.f;
    __syncthreads();
    {
        int pl0 = wv * 2;
        #pragma unroll
        for (int h = 0; h < 8; ++h) {
            acc_s[pl0][h][lane] = agg0[h] * inv_s[pl0 * 8 + h];
            acc_s[pl0 + 1][h][lane] = agg1[h] * inv_s[pl0 * 8 + 8 + h];
        }
    }
    __syncthreads();

    {
        int h = t >> 5, ft = t & 31;
        int f0 = ft * 2;
        float part[8][2];
        #pragma unroll
        for (int pl = 0; pl < 8; ++pl) { part[pl][0] = 0.f; part[pl][1] = 0.f; }
        #pragma unroll
        for (int kg = 0; kg < 16; ++kg) {
            float4 wr0 = *(const float4*)&W4t[(size_t)(kg * TOT + h * 64 + f0 + 0) * 4];
            float4 wr1 = *(const float4*)&W4t[(size_t)(kg * TOT + h * 64 + f0 + 1) * 4];
            #pragma unroll
            for (int pl = 0; pl < 8; ++pl) {
                float4 a4 = *(const float4*)&acc_s[pl][h][kg * 4];
                part[pl][0] = fmaf(a4.x, wr0.x, fmaf(a4.y, wr0.y,
                              fmaf(a4.z, wr0.z, fmaf(a4.w, wr0.w, part[pl][0]))));
                part[pl][1] = fmaf(a4.x, wr1.x, fmaf(a4.y, wr1.y,
                              fmaf(a4.z, wr1.z, fmaf(a4.w, wr1.w, part[pl][1]))));
            }
        }
        __syncthreads();
        #pragma unroll
        for (int pl = 0; pl < 8; ++pl)
            *(float2*)&wp_lds[(pl * 8 + h) * PTS + f0] = make_float2(part[pl][0], part[pl][1]);
    }
    __syncthreads();

    {
        for (int q = t; q < 1024; q += 256) {
            int pl = q >> 7, rem = q & 127;
            int h = rem >> 4, fq = rem & 15;
            int f0 = fq * 4;
            float4 acc4 = *(const float4*)&wp_lds[(pl * 8 + h) * PTS + f0];
            float4 b4 = *(const float4*)&bias[h * 64 + f0];
            acc4.x = gelu_exact(acc4.x + b4.x);
            acc4.y = gelu_exact(acc4.y + b4.y);
            acc4.z = gelu_exact(acc4.z + b4.z);
            acc4.w = gelu_exact(acc4.w + b4.w);
            *(float4*)&out[(size_t)(n * 8 + pl) * TOT + h * 64 + f0] = acc4;
        }
    }
}

// ---------------- layer 3: register-src aggregation + split-h MFMA transform ----------------
// 6000 blocks, 6 blocks/CU; nontemporal out stores (write-once, keep L2 for X gather).
__global__ __launch_bounds__(256, 6) void agg_mfma6(
    const float* __restrict__ X,        // h2 [N*64, 64]
    const float* __restrict__ el, const float* __restrict__ er,  // [N*64, 8]
    const unsigned* __restrict__ wfhi, const unsigned* __restrict__ wflo,
    const float* __restrict__ bias,     // [256]
    const int* __restrict__ row_ptr, const int* __restrict__ csr_src,
    float* __restrict__ out)            // [N*64, 256]
{
    int b = blockIdx.x;                  // 6000 = 1500 n * 4 pg
    int n = b >> 2, pg = b & 3;
    int p0 = pg * 16;
    int r0 = row_ptr[n], deg = row_ptr[n + 1] - r0;
    int t = threadIdx.x, wv = t >> 6, lane = t & 63;
    int pA = p0 + wv * 4;

    __shared__ unsigned accH[4][16][68];   // [h in round][pl][k] packed bf16 hi|lo

    int c = lane & 31;                     // (q,h) = (c>>3, c&7)
    float erv = er[(n * 64 + pA) * 8 + c];

    float agg[4][8];
    #pragma unroll
    for (int q = 0; q < 4; ++q)
        #pragma unroll
        for (int h = 0; h < 8; ++h) agg[q][h] = 0.f;
    float den_half = 0.f;

    for (int c0 = 0; c0 < deg; c0 += 64) {
        int cnt = min(deg - c0, 64);
        int src_r = (lane < cnt) ? csr_src[r0 + c0 + lane] : 0;
        for (int it = 0; it < cnt; it += 4) {
            int i1 = min(it + 1, cnt - 1), i2 = min(it + 2, cnt - 1), i3 = min(it + 3, cnt - 1);
            int s0 = __builtin_amdgcn_readlane(src_r, it);
            int s1 = __builtin_amdgcn_readlane(src_r, i1);
            int s2 = __builtin_amdgcn_readlane(src_r, i2);
            int s3 = __builtin_amdgcn_readlane(src_r, i3);
            bool v1 = it + 1 < cnt, v2 = it + 2 < cnt, v3 = it + 3 < cnt;
            int sA = (lane < 32) ? s0 : s1;
            int sB = (lane < 32) ? s2 : s3;
            float eA = el[(sA * 64 + pA) * 8 + c] + erv;
            float eB = el[(sB * 64 + pA) * 8 + c] + erv;
            eA = eA > 0.f ? eA : 0.2f * eA;
            eB = eB > 0.f ? eB : 0.2f * eB;
            if (lane >= 32 && !v1) eA = -1e30f;
            if (lane < 32 && !v2) eB = -1e30f;
            if (lane >= 32 && !v3) eB = -1e30f;
            float wA = __expf(eA), wB = __expf(eB);
            den_half += wA + wB;
            int xb0 = (s0 * 64 + pA) * 64 + lane;
            int xb1 = (s1 * 64 + pA) * 64 + lane;
            int xb2 = (s2 * 64 + pA) * 64 + lane;
            int xb3 = (s3 * 64 + pA) * 64 + lane;
            float x0[4], x1[4], x2[4], x3[4];
            #pragma unroll
            for (int q = 0; q < 4; ++q) x0[q] = X[xb0 + q * 64];
            #pragma unroll
            for (int q = 0; q < 4; ++q) x1[q] = X[xb1 + q * 64];
            #pragma unroll
            for (int q = 0; q < 4; ++q) x2[q] = X[xb2 + q * 64];
            #pragma unroll
            for (int q = 0; q < 4; ++q) x3[q] = X[xb3 + q * 64];
            #pragma unroll
            for (int q = 0; q < 4; ++q) {
                #pragma unroll
                for (int h = 0; h < 8; ++h) {
                    agg[q][h] = fmaf(rdlanef(wA, q * 8 + h), x0[q], agg[q][h]);
                    agg[q][h] = fmaf(rdlanef(wA, 32 + q * 8 + h), x1[q], agg[q][h]);
                    agg[q][h] = fmaf(rdlanef(wB, q * 8 + h), x2[q], agg[q][h]);
                    agg[q][h] = fmaf(rdlanef(wB, 32 + q * 8 + h), x3[q], agg[q][h]);
                }
            }
        }
    }
    float den = den_half + __shfl(den_half, lane ^ 32);
    float inv = deg ? 1.f / den : 0.f;

    int m16 = lane & 15, g = lane >> 4;
    #pragma unroll
    for (int r = 0; r < 2; ++r) {
        if (r) __syncthreads();
        #pragma unroll
        for (int q = 0; q < 4; ++q) {
            int pl = wv * 4 + q;
            #pragma unroll
            for (int hh = 0; hh < 4; ++hh) {
                int h = 4 * r + hh;
                float iv = rdlanef(inv, q * 8 + h);
                accH[hh][pl][lane] = packbf(agg[q][h] * iv);
            }
        }
        __syncthreads();
        int h = 4 * r + wv;
        bf16x8 a_hi[2], a_lo[2];
        #pragma unroll
        for (int ks = 0; ks < 2; ++ks) {
            const unsigned* ap = &accH[wv][m16][ks * 32 + g * 8];
            uint4 q0 = *(const uint4*)ap;
            uint4 q1 = *(const uint4*)(ap + 4);
            a_hi[ks][0] = (short)(q0.x & 0xffffu); a_lo[ks][0] = (short)(q0.x >> 16);
            a_hi[ks][1] = (short)(q0.y & 0xffffu); a_lo[ks][1] = (short)(q0.y >> 16);
            a_hi[ks][2] = (short)(q0.z & 0xffffu); a_lo[ks][2] = (short)(q0.z >> 16);
            a_hi[ks][3] = (short)(q0.w & 0xffffu); a_lo[ks][3] = (short)(q0.w >> 16);
            a_hi[ks][4] = (short)(q1.x & 0xffffu); a_lo[ks][4] = (short)(q1.x >> 16);
            a_hi[ks][5] = (short)(q1.y & 0xffffu); a_lo[ks][5] = (short)(q1.y >> 16);
            a_hi[ks][6] = (short)(q1.z & 0xffffu); a_lo[ks][6] = (short)(q1.z >> 16);
            a_hi[ks][7] = (short)(q1.w & 0xffffu); a_lo[ks][7] = (short)(q1.w >> 16);
        }
        #pragma unroll
        for (int nt = 0; nt < 2; ++nt) {
            f32x4 D = {0.f, 0.f, 0.f, 0.f};
            #pragma unroll
            for (int ks = 0; ks < 2; ++ks) {
                size_t fb = (size_t)(((h * 2 + nt) * 2 + ks) * 64 + lane) * 4;
                bf16x8 b_hi = *(const bf16x8*)&wfhi[fb];
                bf16x8 b_lo = *(const bf16x8*)&wflo[fb];
                D = __builtin_amdgcn_mfma_f32_16x16x32_bf16(a_hi[ks], b_hi, D, 0, 0, 0);
                D = __builtin_amdgcn_mfma_f32_16x16x32_bf16(a_hi[ks], b_lo, D, 0, 0, 0);
                D = __builtin_amdgcn_mfma_f32_16x16x32_bf16(a_lo[ks], b_hi, D, 0, 0, 0);
            }
            float bv = bias[h * 32 + nt * 16 + m16];
            size_t ob = ((size_t)(n * 64) + p0 + g * 4) * 256 + h * 32 + nt * 16 + m16;
            __builtin_nontemporal_store(D[0] + bv, &out[ob]);
            __builtin_nontemporal_store(D[1] + bv, &out[ob + 256]);
            __builtin_nontemporal_store(D[2] + bv, &out[ob + 512]);
            __builtin_nontemporal_store(D[3] + bv, &out[ob + 768]);
        }
    }
}

// ---------------- launch ----------------

extern "C" void kernel_launch(void* const* d_in, const int* in_sizes, int n_in,
                              void* d_out, int out_size, void* d_ws, size_t ws_size,
                              hipStream_t stream) {
    const float* node = (const float*)d_in[0];
    const int* src = (const int*)d_in[1];
    const int* dst = (const int*)d_in[2];
    const float* W1 = (const float*)d_in[3];
    const float* al1 = (const float*)d_in[4];
    const float* ar1 = (const float*)d_in[5];
    const float* b1 = (const float*)d_in[6];
    const float* W2 = (const float*)d_in[7];
    const float* al2 = (const float*)d_in[8];
    const float* ar2 = (const float*)d_in[9];
    const float* b2 = (const float*)d_in[10];
    const float* W3 = (const float*)d_in[11];
    const float* al3 = (const float*)d_in[12];
    const float* ar3 = (const float*)d_in[13];
    const float* b3 = (const float*)d_in[14];
    float* out = (float*)d_out;

    char* ws = (char*)d_ws;
    size_t off = 0;
    auto alloc = [&](size_t nb) -> char* {
        char* q = ws + off;
        off += (nb + 255) & ~(size_t)255;
        return q;
    };
    int* counts   = (int*)alloc((N_NODES + 1) * sizeof(int));
    int* cursor   = (int*)alloc(N_NODES * sizeof(int));
    int* row_ptr  = (int*)alloc((N_NODES + 1) * sizeof(int));
    int* tmp_eid  = (int*)alloc(N_EDGES * sizeof(int));
    int* csr_src  = (int*)alloc(N_EDGES * sizeof(int));
    float* feat1  = (float*)alloc((size_t)N_NODES * 8 * 64 * 4);
    float* el1    = (float*)alloc((size_t)N_NODES * 8 * 4);
    float* er1    = (float*)alloc((size_t)N_NODES * 8 * 4);
    float* h1     = (float*)alloc((size_t)N_NODES * 8 * 64 * 4);
    float* aleff2 = (float*)alloc(8 * 64 * 4);
    float* areff2 = (float*)alloc(8 * 64 * 4);
    float* el2    = (float*)alloc((size_t)N_NODES * 8 * 8 * 4);
    float* er2    = (float*)alloc((size_t)N_NODES * 8 * 8 * 4);
    float* h2     = (float*)alloc((size_t)N_NODES * 64 * 64 * 4);
    float* aleff3 = (float*)alloc(8 * 64 * 4);
    float* areff3 = (float*)alloc(8 * 64 * 4);
    float* el3    = (float*)alloc((size_t)N_NODES * 64 * 8 * 4);
    float* er3    = (float*)alloc((size_t)N_NODES * 64 * 8 * 4);
    float* W4t2   = (float*)alloc((size_t)16 * 512 * 4 * 4);
    unsigned* wfhi = (unsigned*)alloc((size_t)8192 * 4);
    unsigned* wflo = (unsigned*)alloc((size_t)8192 * 4);

    const int PREP_T = 1536 + 1536 + 1024 + 1024 + 16 * 512 * 4 + 16384;
    prep_kernel<<<(PREP_T + 255) / 256, 256, 0, stream>>>(
        W2, al2, ar2, W3, al3, ar3, aleff2, areff2, aleff3, areff3, W4t2, wfhi, wflo,
        counts, cursor);

    hist_kernel<<<(N_EDGES + 255) / 256, 256, 0, stream>>>(dst, counts);
    scan_kernel<<<1, 256, 0, stream>>>(counts, row_ptr);
    scatter_kernel<<<(N_EDGES + 255) / 256, 256, 0, stream>>>(dst, row_ptr, cursor, tmp_eid);
    sort_csr_kernel<<<(N_NODES * 64 + 255) / 256, 256, 0, stream>>>(row_ptr, tmp_eid, src, csr_src);

    // ---- layer 1 ----
    dim3 g1((512 + GN - 1) / GN, (N_NODES + GM - 1) / GM);
    gemm_f32<<<g1, 256, 0, stream>>>(node, W1, feat1, N_NODES, 512, IN_FEAT);
    elr_feat_kernel<<<(N_NODES * 8 + 255) / 256, 256, 0, stream>>>(feat1, al1, ar1, el1, er1, N_NODES * 8);
    agg_l1<<<N_NODES, 256, 0, stream>>>(feat1, el1, er1, b1, row_ptr, csr_src, h1);

    // ---- layer 2 ----
    elr_row_kernel<<<(N_NODES * 8 + 255) / 256, 256, 0, stream>>>(h1, aleff2, areff2, el2, er2, N_NODES * 8);
    agg_fused5<<<N_NODES, 256, 0, stream>>>(h1, el2, er2, W4t2, b2, row_ptr, csr_src, h2);

    // ---- layer 3 ----
    elr_row_kernel<<<(N_NODES * 64 + 255) / 256, 256, 0, stream>>>(h2, aleff3, areff3, el3, er3, N_NODES * 64);
    agg_mfma6<<<N_NODES * 4, 256, 0, stream>>>(h2, el3, er3, wfhi, wflo, b3, row_ptr, csr_src, out);
}